// Round 2
// baseline (769.022 us; speedup 1.0000x reference)
//
#include <hip/hip_runtime.h>
#include <math.h>

// Problem constants
#define NB 4096          // batch B -> one block per b
#define CC 128           // channels (GEMM K)
#define TT 10
#define JJ 22
#define MM 220           // sites per b = T*J (14 m-tiles of 16, last 4 rows dead)
#define OUT0_N 19824640  // 4096*10*22*22
#define OUT1_N 9011200   // 4096*22*10*10

typedef __attribute__((ext_vector_type(8))) short bf16x8;
typedef __attribute__((ext_vector_type(8))) unsigned short u16x8;
typedef __attribute__((ext_vector_type(4))) float f32x4;

// Static device scratch for the bf16 weight-fragment array (64 KB).
// 4096 fragments x 8 bf16: fragment f=(nt*4+kf)*64+lane holds
//   Wb[n = nt*16 + (lane&15)][k = kf*32 + (lane>>4)*8 + j], j=0..7
// which is exactly the per-lane B-operand of mfma_f32_16x16x32_bf16.
// Module-scope __device__ avoids any dependence on ws_size (no OOB risk).
__device__ __align__(16) unsigned short g_wf[32768];

// fp32 -> bf16 bits, round-to-nearest-even
__device__ __forceinline__ unsigned f2bf(float f) {
  union { float f; unsigned u; } v; v.f = f;
  return (v.u + 0x7FFFu + ((v.u >> 16) & 1u)) >> 16;
}

// ---------------------------------------------------------------------------
// Prep: Wb = [W_s ; W_t] (256x128 f32) -> bf16 fragment-major in g_wf.
// Written once per launch (16 blocks x 256 thr), read by all 4096 main blocks
// (64 KB -> L2-hot broadcast).
// ---------------------------------------------------------------------------
__global__ __launch_bounds__(256) void prep_w(
    const float* __restrict__ Ws, const float* __restrict__ Wt)
{
  const int id   = blockIdx.x * 256 + threadIdx.x;  // 0..4095
  const int lane = id & 63;
  const int kf   = (id >> 6) & 3;
  const int nt   = id >> 8;
  const int n    = nt * 16 + (lane & 15);
  const int k0   = kf * 32 + (lane >> 4) * 8;
  const float* row = (n < 128) ? (Ws + n * CC) : (Wt + (n - 128) * CC);
  u16x8 v;
  #pragma unroll
  for (int j = 0; j < 8; ++j) v[j] = (unsigned short)f2bf(row[k0 + j]);
  *reinterpret_cast<u16x8*>(g_wf + (size_t)id * 8) = v;
}

// ---------------------------------------------------------------------------
// Main: one block per b. 896 threads = 14 waves = 7 m-groups x 2 n-halves.
// Wave (mg, half): rows m in [mg*32, mg*32+32) x n-half (0 => spatial -> ds_l,
// 1 => temporal -> dt_l). Softmax cancellation (softmax_j(s_i+d_j) ==
// softmax_j(d_j)) makes a_src dead. No W staging, no LDS GEMM tile, one
// barrier total before the epilogues.
// ---------------------------------------------------------------------------
__global__ __launch_bounds__(896, 4) void dms_main(
    const float* __restrict__ src,
    const float* __restrict__ a_dst_s,
    const float* __restrict__ a_dst_t,
    const float* __restrict__ sa_bias,
    const float* __restrict__ ta_bias,
    float* __restrict__ out)
{
  __shared__ float ds_l[MM];   // d_s per site
  __shared__ float dt_l[MM];   // d_t per site

  const int tid  = threadIdx.x;
  const int w    = tid >> 6;     // wave 0..13
  const int lane = tid & 63;
  const int l15  = lane & 15;
  const int quad = lane >> 4;
  const int mg   = w >> 1;       // m-group 0..6
  const int half = w & 1;        // 0 = spatial (n<128), 1 = temporal
  const int b    = blockIdx.x;

  const float* srcb = src + (size_t)b * (CC * MM);

  // ---- A fragments: direct global loads, cvt to bf16 ----
  // MFMA A layout (16x16x32): A[m = lane&15][k = quad*8 + j]
  // src[b,c,m]: c-major, m contiguous -> 16-lane groups coalesce per load.
  bf16x8 Aa[2][4];
  #pragma unroll
  for (int mtp = 0; mtp < 2; ++mtp) {
    int m = (mg * 2 + mtp) * 16 + l15;
    if (m > MM - 1) m = MM - 1;  // clamp: rows >=220 are dead, never written
    #pragma unroll
    for (int kfi = 0; kfi < 4; ++kfi) {
      const float* p = srcb + (kfi * 32 + quad * 8) * MM + m;
      bf16x8 f;
      #pragma unroll
      for (int j = 0; j < 8; ++j)
        f[j] = (short)f2bf(p[j * MM]);
      Aa[mtp][kfi] = f;
    }
  }

  // ---- GEMM over this wave's n-half: fused lrelu + a-weighted reduce ----
  // B fragments straight from g_wf (coalesced 16B/lane, L2-hot).
  // C/D layout: col = lane&15 (n), row = quad*4 + r (m).
  const bf16x8* wfv = reinterpret_cast<const bf16x8*>(g_wf);
  const float*  ap  = half ? a_dst_t : a_dst_s;
  const int fbase   = half * (8 * 4 * 64);  // fragment base for this n-half

  f32x4 part0 = {0,0,0,0}, part1 = {0,0,0,0};
  #pragma unroll
  for (int nt8 = 0; nt8 < 8; ++nt8) {
    f32x4 acc0 = {0,0,0,0}, acc1 = {0,0,0,0};
    #pragma unroll
    for (int kfi = 0; kfi < 4; ++kfi) {
      bf16x8 bb = wfv[fbase + (nt8 * 4 + kfi) * 64 + lane];
      acc0 = __builtin_amdgcn_mfma_f32_16x16x32_bf16(Aa[0][kfi], bb, acc0, 0, 0, 0);
      acc1 = __builtin_amdgcn_mfma_f32_16x16x32_bf16(Aa[1][kfi], bb, acc1, 0, 0, 0);
    }
    float av = ap[nt8 * 16 + l15];
    #pragma unroll
    for (int r = 0; r < 4; ++r) {
      float x0 = acc0[r]; x0 = (x0 >= 0.f) ? x0 : 0.2f * x0;
      float x1 = acc1[r]; x1 = (x1 >= 0.f) ? x1 : 0.2f * x1;
      part0[r] += av * x0;
      part1[r] += av * x1;
    }
  }

  // reduce across the 16 lanes sharing a row (low 4 lane bits enumerate n)
  #pragma unroll
  for (int mk = 1; mk <= 8; mk <<= 1) {
    #pragma unroll
    for (int r = 0; r < 4; ++r) {
      part0[r] += __shfl_xor(part0[r], mk);
      part1[r] += __shfl_xor(part1[r], mk);
    }
  }
  float* dl = half ? dt_l : ds_l;
  if (l15 == 0) {
    #pragma unroll
    for (int r = 0; r < 4; ++r) {
      int m0 = (mg * 2) * 16 + quad * 4 + r;
      if (m0 < MM) dl[m0] = part0[r];
      int m1 = (mg * 2 + 1) * 16 + quad * 4 + r;
      if (m1 < MM) dl[m1] = part1[r];
    }
  }
  __syncthreads();

  // ---- spatial epilogue: softmax over j per (b,t); out0[b,t,i,j] ----
  if (w < TT) {
    const int t = w;
    float e = (lane < JJ) ? ds_l[t * JJ + lane] : -1e30f;
    float mx = e;
    #pragma unroll
    for (int mk = 1; mk < 64; mk <<= 1) mx = fmaxf(mx, __shfl_xor(mx, mk));
    float pp = (lane < JJ) ? __expf(e - mx) : 0.f;
    float ss = pp;
    #pragma unroll
    for (int mk = 1; mk < 64; mk <<= 1) ss += __shfl_xor(ss, mk);
    pp = pp / ss;
    float* o = out + (size_t)(b * TT + t) * (JJ * JJ);
    #pragma unroll
    for (int base = 0; base < 484; base += 64) {
      int oi = base + lane;
      int jdx = oi % JJ;              // < 22 even for oi >= 484
      float v = __shfl(pp, jdx);      // all 64 lanes execute the shfl
      if (oi < 484) o[oi] = v + sa_bias[oi];
    }
  }

  // ---- temporal epilogue: softmax over t per (b,j); out1[b,j,i,t] ----
  float* out1 = out + (size_t)OUT0_N;
  for (int jdx = w; jdx < JJ; jdx += 14) {
    float e = (lane < TT) ? dt_l[lane * JJ + jdx] : -1e30f;
    float mx = e;
    #pragma unroll
    for (int mk = 1; mk < 64; mk <<= 1) mx = fmaxf(mx, __shfl_xor(mx, mk));
    float qq = (lane < TT) ? __expf(e - mx) : 0.f;
    float ss = qq;
    #pragma unroll
    for (int mk = 1; mk < 64; mk <<= 1) ss += __shfl_xor(ss, mk);
    qq = qq / ss;
    float* o = out1 + (size_t)(b * JJ + jdx) * (TT * TT);
    #pragma unroll
    for (int base = 0; base < 128; base += 64) {
      int oi = base + lane;
      int tdx = oi % TT;
      float v = __shfl(qq, tdx);
      if (oi < 100) o[oi] = v + ta_bias[oi];
    }
  }

  // 4 trailing scalar zeros of the output tuple
  if (b == 0 && tid < 4) out[(size_t)OUT0_N + OUT1_N + tid] = 0.f;
}

extern "C" void kernel_launch(void* const* d_in, const int* in_sizes, int n_in,
                              void* d_out, int out_size, void* d_ws, size_t ws_size,
                              hipStream_t stream) {
  const float* src = (const float*)d_in[0];
  const float* Ws  = (const float*)d_in[1];
  // d_in[2] = a_src_s, d_in[5] = a_src_t: mathematically dead (softmax cancel)
  const float* ads = (const float*)d_in[3];
  const float* Wt  = (const float*)d_in[4];
  const float* adt = (const float*)d_in[6];
  const float* sab = (const float*)d_in[7];
  const float* tab = (const float*)d_in[8];
  prep_w<<<16, 256, 0, stream>>>(Ws, Wt);
  dms_main<<<NB, 896, 0, stream>>>(src, ads, adt, sab, tab, (float*)d_out);
}